// Round 8
// baseline (330.869 us; speedup 1.0000x reference)
//
#include <hip/hip_runtime.h>
#include <hip/hip_bf16.h>
#include <math.h>

typedef _Float16 f16;
typedef __attribute__((ext_vector_type(8))) _Float16 f16x8;
typedef __attribute__((ext_vector_type(4))) _Float16 f16x4;
typedef __attribute__((ext_vector_type(4))) float f32x4;

namespace {
constexpr int B = 4, L = 2048, D = 512, NH = 8, DH = 64;
}

__device__ __forceinline__ float dpp_xor1(float x) {   // lane ^= 1 (quad_perm 1,0,3,2)
    return __int_as_float(__builtin_amdgcn_update_dpp(0, __float_as_int(x), 0xB1, 0xF, 0xF, true));
}
__device__ __forceinline__ float dpp_xor2(float x) {   // lane ^= 2 (quad_perm 2,3,0,1)
    return __int_as_float(__builtin_amdgcn_update_dpp(0, __float_as_int(x), 0x4E, 0xF, 0xF, true));
}
__device__ __forceinline__ float dpp_ror4(float x) {   // rotate 16-lane row by 4
    return __int_as_float(__builtin_amdgcn_update_dpp(0, __float_as_int(x), 0x124, 0xF, 0xF, true));
}
__device__ __forceinline__ float dpp_ror8(float x) {   // rotate 16-lane row by 8
    return __int_as_float(__builtin_amdgcn_update_dpp(0, __float_as_int(x), 0x128, 0xF, 0xF, true));
}

// ---- E cast: fp32 -> fp16 (131072 elems) ----
__global__ __launch_bounds__(256)
void ecast_kernel(const float* __restrict__ E, f16* __restrict__ Ef) {
    int i4 = (blockIdx.x * 256 + threadIdx.x) * 4;
    float4 x = *(const float4*)(E + i4);
    *(f16x4*)(Ef + i4) = (f16x4){(f16)x.x, (f16)x.y, (f16)x.z, (f16)x.w};
}

// ---- X cast: q/k/v fp32 -> f16 planes ----
__global__ __launch_bounds__(256)
void xcast_kernel(const float* __restrict__ q, const float* __restrict__ k,
                  const float* __restrict__ v, f16* __restrict__ Xf) {
    const int sel = blockIdx.y;
    const float* X = (sel == 0) ? q : (sel == 1) ? k : v;
    const size_t i4 = ((size_t)blockIdx.x * 256 + threadIdx.x) * 4;
    float4 x = *(const float4*)(X + i4);
    *(f16x4*)(Xf + (size_t)sel * ((size_t)B * L * D) + i4) =
        (f16x4){(f16)x.x, (f16)x.y, (f16)x.z, (f16)x.w};
}

// ---- W transpose+cast: W[k][n] fp32 -> Wt[sel][n][k] fp16, 64x64 tiles ----
__global__ __launch_bounds__(256)
void wtrans_kernel(const float* __restrict__ Wq, const float* __restrict__ Wk,
                   const float* __restrict__ Wv, f16* __restrict__ Wt) {
    __shared__ f16 Ws[64 * 65];
    const int sel = blockIdx.z;
    const float* W = (sel == 0) ? Wq : (sel == 1) ? Wk : Wv;
    f16* Wo = Wt + (size_t)sel * D * D;
    const int k0 = blockIdx.x * 64, n0 = blockIdx.y * 64;
    const int t = threadIdx.x;
#pragma unroll
    for (int i = 0; i < 16; ++i) {
        int idx = 256 * i + t;
        int r = idx >> 6, c = idx & 63;
        Ws[r * 65 + c] = (f16)W[(size_t)(k0 + r) * D + n0 + c];
    }
    __syncthreads();
    const int c = t >> 2, kseg = t & 3;
    f16x8 r0, r1;
#pragma unroll
    for (int j = 0; j < 8; ++j) r0[j] = Ws[(kseg * 16 + j) * 65 + c];
#pragma unroll
    for (int j = 0; j < 8; ++j) r1[j] = Ws[(kseg * 16 + 8 + j) * 65 + c];
    f16* o = Wo + (size_t)(n0 + c) * D + k0 + kseg * 16;
    *(f16x8*)o = r0;
    *(f16x8*)(o + 8) = r1;
}

// ---- fused projections: C = Xf(f16) . W, fp16 MFMA single-pass (R4-verified) ----
__global__ __launch_bounds__(256, 4)
void proj_gemm(const f16* __restrict__ Xf, const f16* __restrict__ Wt,
               f16* __restrict__ Qf, f16* __restrict__ Kf, f16* __restrict__ Vtf) {
    __shared__ f16 As[128 * 72];
    __shared__ f16 Bs[64 * 72];
    const int flat = blockIdx.x;
    const int wg = (flat & 7) * 192 + (flat >> 3);   // 1536 = 8 XCDs * 192
    const int by = wg % 24, bx = wg / 24;            // by fast: heads share X panel
    const int sel = by >> 3, h = by & 7;
    const int m0 = bx * 128;
    const f16* X = Xf + (size_t)sel * ((size_t)B * L * D);
    const f16* Bt = Wt + (size_t)sel * D * D + (size_t)h * 64 * D;
    const int t = threadIdx.x, wid = t >> 6, lane = t & 63;
    const int quad = lane >> 4, col = lane & 15;
    const int mw = wid * 32;

    f32x4 acc[2][4];
#pragma unroll
    for (int i = 0; i < 2; ++i)
#pragma unroll
        for (int j = 0; j < 4; ++j) acc[i][j] = (f32x4){0.f, 0.f, 0.f, 0.f};

    f16x8 xa[4];
    f16x8 breg[2];
    auto loadG = [&](int k0) {
#pragma unroll
        for (int i = 0; i < 4; ++i) {
            int idx = 256 * i + t;
            int r = idx >> 3, ch = idx & 7;            // 128 rows x 8 chunks
            xa[i] = *(const f16x8*)(X + (size_t)(m0 + r) * D + k0 + ch * 8);
        }
#pragma unroll
        for (int i = 0; i < 2; ++i) {
            int idx = 256 * i + t;
            int r = idx >> 3, ch = idx & 7;            // 64 rows x 8 chunks
            breg[i] = *(const f16x8*)(Bt + (size_t)r * D + k0 + ch * 8);
        }
    };
    auto storeL = [&]() {
#pragma unroll
        for (int i = 0; i < 4; ++i) {
            int idx = 256 * i + t;
            int r = idx >> 3, ch = idx & 7;
            *(f16x8*)(As + r * 72 + ch * 8) = xa[i];
        }
#pragma unroll
        for (int i = 0; i < 2; ++i) {
            int idx = 256 * i + t;
            int r = idx >> 3, ch = idx & 7;
            *(f16x8*)(Bs + r * 72 + ch * 8) = breg[i];
        }
    };

    loadG(0);
    for (int k0 = 0; k0 < D; k0 += 64) {
        __syncthreads();
        storeL();
        __syncthreads();
        if (k0 + 64 < D) loadG(k0 + 64);
#pragma unroll
        for (int ks = 0; ks < 2; ++ks) {
            f16x8 af[2], bf[4];
#pragma unroll
            for (int mt = 0; mt < 2; ++mt)
                af[mt] = *(const f16x8*)(As + (mw + mt * 16 + col) * 72 + quad * 8 + ks * 32);
#pragma unroll
            for (int nt = 0; nt < 4; ++nt)
                bf[nt] = *(const f16x8*)(Bs + (nt * 16 + col) * 72 + quad * 8 + ks * 32);
#pragma unroll
            for (int mt = 0; mt < 2; ++mt)
#pragma unroll
                for (int nt = 0; nt < 4; ++nt)
                    acc[mt][nt] = __builtin_amdgcn_mfma_f32_16x16x32_f16(af[mt], bf[nt], acc[mt][nt], 0, 0, 0);
        }
    }

    if (sel < 2) {
        f16* Y = (sel == 0) ? Qf : Kf;
#pragma unroll
        for (int mt = 0; mt < 2; ++mt)
#pragma unroll
            for (int nt = 0; nt < 4; ++nt)
#pragma unroll
                for (int reg = 0; reg < 4; ++reg) {
                    int m = m0 + mw + mt * 16 + quad * 4 + reg;
                    int bb = m >> 11, l = m & 2047, d = nt * 16 + col;
                    Y[((size_t)(bb * NH + h) * L + l) * DH + d] = (f16)acc[mt][nt][reg];
                }
    } else {
        __syncthreads();                 // As frag reads done; reuse as Cs[64][136]
        f16* Cs = As;
#pragma unroll
        for (int mt = 0; mt < 2; ++mt)
#pragma unroll
            for (int nt = 0; nt < 4; ++nt)
#pragma unroll
                for (int reg = 0; reg < 4; ++reg) {
                    int d = nt * 16 + col;
                    int lc = mw + mt * 16 + quad * 4 + reg;
                    Cs[d * 136 + lc] = (f16)acc[mt][nt][reg];
                }
        __syncthreads();
        const int dd = t >> 2, seg = t & 3;
        const int bb = m0 >> 11, l0 = m0 & 2047;
        f16* Yv = Vtf + ((size_t)(bb * NH + h) * DH + dd) * L + l0 + seg * 32;
#pragma unroll
        for (int j = 0; j < 4; ++j)
            *(f16x8*)(Yv + j * 8) = *(const f16x8*)(Cs + dd * 136 + seg * 32 + j * 8);
    }
}

// ---- flash attention, fp16 MFMA, reg-prefetch K/V pipeline ----
// R4 base (verified 221us) + three surgical cuts:
//  * P-buf XOR swizzle ((r&8)<<1, R5-verified-correct): kills the 4-way
//    quad0/quad2 bank aliasing on the 16 scalar P writes per tile
//  * defer-max ballot skip (T13, THR=0 -> bit-exact): skip alpha-exp +
//    O/sacc rescale when no row's max grew (wave-uniform branch)
//  * all-DPP max tree (ror4/ror8, R7-verified); loadKV issued before the
//    2nd barrier so global loads fly during barrier skew
__global__ __launch_bounds__(256, 4)
void attn_kernel(const f16* __restrict__ Qf, const f16* __restrict__ Kf,
                 const f16* __restrict__ Vtf, const f16* __restrict__ Ef,
                 float* __restrict__ out) {
    __shared__ f16 KfS[64 * 72];
    __shared__ f16 VfS[64 * 72];
    __shared__ f16 Pbuf[4][16 * 72];

    const int t = threadIdx.x, wid = t >> 6, lane = t & 63;
    const int quad = lane >> 4, col = lane & 15;
    const int l0w = blockIdx.x * 64 + wid * 16;
    const int h = blockIdx.y, bb = blockIdx.z;
    const size_t head = (size_t)(bb * NH + h) * (size_t)(L * DH);
    const f16* qf = Qf + head;
    const f16* kf = Kf + head;
    const f16* vt = Vtf + head;      // [dh][L]
    f16* Pw = Pbuf[wid];

    const f16x8 ones8 = {(f16)1.f, (f16)1.f, (f16)1.f, (f16)1.f,
                         (f16)1.f, (f16)1.f, (f16)1.f, (f16)1.f};

    f16x8 qF[2], qS[2];
    {
        const int m = l0w + col;
        const int mS = min(m + 1, L - 1);   // row L never actually used
#pragma unroll
        for (int ks = 0; ks < 2; ++ks) {
            const int off = quad * 8 + ks * 32;
            qF[ks] = *(const f16x8*)(qf + (size_t)m * DH + off);
            qS[ks] = *(const f16x8*)(qf + (size_t)mS * DH + off);
        }
    }

    f16x8 kreg[2], vreg[2];
    auto loadKV = [&](int c0) {
#pragma unroll
        for (int i = 0; i < 2; ++i) {
            int idx = 256 * i + t;
            int r = idx >> 3, ch = idx & 7;
            kreg[i] = *(const f16x8*)(kf + (size_t)(c0 + r) * DH + ch * 8);
            vreg[i] = *(const f16x8*)(vt + (size_t)r * L + c0 + ch * 8);
        }
    };

    f32x4 O[4];
#pragma unroll
    for (int i = 0; i < 4; ++i) O[i] = (f32x4){0.f, 0.f, 0.f, 0.f};
    f32x4 sacc = (f32x4){0.f, 0.f, 0.f, 0.f};
    float mrow[4] = {-1e30f, -1e30f, -1e30f, -1e30f};

    loadKV(0);
    for (int c0 = 0; c0 < L; c0 += 64) {
        __syncthreads();   // all waves done reading previous K/V tile
#pragma unroll
        for (int i = 0; i < 2; ++i) {
            int idx = 256 * i + t;
            int r = idx >> 3, ch = idx & 7;
            *(f16x8*)(KfS + r * 72 + ch * 8) = kreg[i];
            *(f16x8*)(VfS + r * 72 + ch * 8) = vreg[i];
        }
        if (c0 + 64 < L) loadKV(c0 + 64);   // issue before barrier: flies during skew
        __syncthreads();

        const int d0 = c0 - l0w;

        // ---- S = Q K^T (fp16 single pass) ----
        f32x4 S[4];
        __builtin_amdgcn_s_setprio(1);
#pragma unroll
        for (int ns = 0; ns < 4; ++ns) {
            S[ns] = (f32x4){0.f, 0.f, 0.f, 0.f};
#pragma unroll
            for (int ks = 0; ks < 2; ++ks) {
                f16x8 bh = *(const f16x8*)(KfS + (ns * 16 + col) * 72 + quad * 8 + ks * 32);
                S[ns] = __builtin_amdgcn_mfma_f32_16x16x32_f16(qF[ks], bh, S[ns], 0, 0, 0);
            }
        }
        __builtin_amdgcn_s_setprio(0);

        // ---- Srel: G = Q . E-window^T, scatter via intra-quad shuffles ----
        const bool doA = (d0 <= 15);
        const bool doB = (d0 >= -61);
#pragma unroll 1
        for (int pass = 0; pass < 2; ++pass) {
            if ((pass == 0 && !doA) || (pass == 1 && !doB)) continue;
            const int jbase = (pass == 0) ? (d0 + L - 16) : (d0 - 17);
            f32x4 G[5];
#pragma unroll
            for (int g = 0; g < 5; ++g) {
                int er = min(max(jbase + g * 16 + col, 0), L - 1);
                G[g] = (f32x4){0.f, 0.f, 0.f, 0.f};
                const size_t eb = (size_t)er * DH + quad * 8;
#pragma unroll
                for (int ks = 0; ks < 2; ++ks) {
                    f16x8 e8 = *(const f16x8*)(Ef + eb + ks * 32);
                    G[g] = __builtin_amdgcn_mfma_f32_16x16x32_f16(
                               (pass == 0) ? qF[ks] : qS[ks], e8, G[g], 0, 0, 0);
                }
            }
#pragma unroll
            for (int reg = 0; reg < 4; ++reg) {
                const int r  = quad * 4 + reg;
                const int jj = col - r + 15;            // [0,30]
                const int src = quad * 16 + (jj & 15);  // same quad holds row r
#pragma unroll
                for (int ns = 0; ns < 4; ++ns) {
                    float v0 = __shfl(G[ns][reg], src, 64);
                    float v1 = __shfl(G[ns + 1][reg], src, 64);
                    float val = (jj < 16) ? v0 : v1;
                    const int rel = d0 + ns * 16 + col - r;
                    const bool use = (pass == 0) ? (rel <= 0) : (rel >= 2);
                    if (use) S[ns][reg] += val;
                }
            }
        }

        // ---- online softmax (rows in 16-lane groups); sum via MFMA below ----
#pragma unroll
        for (int reg = 0; reg < 4; ++reg) {
            float tm = fmaxf(fmaxf(S[0][reg], S[1][reg]), fmaxf(S[2][reg], S[3][reg]));
            tm = fmaxf(tm, dpp_xor1(tm));
            tm = fmaxf(tm, dpp_xor2(tm));
            tm = fmaxf(tm, dpp_ror4(tm));
            tm = fmaxf(tm, dpp_ror8(tm));
            // defer-max (THR=0, bit-exact): rescale only if some row's max grew
            if (__ballot(tm > mrow[reg]) != 0ull) {
                const float mnew  = fmaxf(mrow[reg], tm);
                const float alpha = __expf(mrow[reg] - mnew);
                mrow[reg] = mnew;
                sacc[reg] *= alpha;
#pragma unroll
                for (int ns = 0; ns < 4; ++ns) O[ns][reg] *= alpha;
            }
            const float mloc = mrow[reg];
            const int r = quad * 4 + reg;
            const int sw = (r & 8) << 1;          // XOR 16 elems for rows 8..15
#pragma unroll
            for (int ns = 0; ns < 4; ++ns) {
                float p = __expf(S[ns][reg] - mloc);
                Pw[r * 72 + ((ns * 16 + col) ^ sw)] = (f16)p;
            }
        }
        // wave-private Pw write->read ordered by lgkmcnt within the wave

        // ---- O += P V ; sacc += rowsum(P) via ones-fragment ----
        const int rsw = (col & 8) << 1;
        f16x8 pA[2];
        pA[0] = *(const f16x8*)(Pw + col * 72 + ((quad * 8) ^ rsw));
        pA[1] = *(const f16x8*)(Pw + col * 72 + ((quad * 8 + 32) ^ rsw));
        __builtin_amdgcn_s_setprio(1);
        sacc = __builtin_amdgcn_mfma_f32_16x16x32_f16(pA[0], ones8, sacc, 0, 0, 0);
        sacc = __builtin_amdgcn_mfma_f32_16x16x32_f16(pA[1], ones8, sacc, 0, 0, 0);
#pragma unroll
        for (int ns = 0; ns < 4; ++ns) {
#pragma unroll
            for (int ks = 0; ks < 2; ++ks) {
                f16x8 v8 = *(const f16x8*)(VfS + (ns * 16 + col) * 72 + quad * 8 + ks * 32);
                O[ns] = __builtin_amdgcn_mfma_f32_16x16x32_f16(pA[ks], v8, O[ns], 0, 0, 0);
            }
        }
        __builtin_amdgcn_s_setprio(0);
    }

#pragma unroll
    for (int reg = 0; reg < 4; ++reg) {
        const int l = l0w + quad * 4 + reg;
        const float inv = 1.0f / (sacc[reg] * 8.0f);
        float* o = out + ((size_t)bb * L + l) * D + h * DH;
#pragma unroll
        for (int ns = 0; ns < 4; ++ns)
            o[ns * 16 + col] = O[ns][reg] * inv;
    }
}

extern "C" void kernel_launch(void* const* d_in, const int* in_sizes, int n_in,
                              void* d_out, int out_size, void* d_ws, size_t ws_size,
                              hipStream_t stream) {
    const float* q  = (const float*)d_in[0];
    const float* k  = (const float*)d_in[1];
    const float* v  = (const float*)d_in[2];
    const float* Wq = (const float*)d_in[3];
    const float* Wk = (const float*)d_in[4];
    const float* Wv = (const float*)d_in[5];
    const float* E  = (const float*)d_in[6];
    float* out = (float*)d_out;

    // ws (fp16 elems): Qf|Kf|Vtf (4M each) | Wt (768K) | Ef (128K) | Xf (12M) ~ 50MB
    const size_t plane = (size_t)B * NH * L * DH;    // 4,194,304 (= B*L*D)
    f16* Qf  = (f16*)d_ws;
    f16* Kfp = Qf + plane;
    f16* Vtf = Kfp + plane;
    f16* Wt  = Vtf + plane;
    f16* Ef  = Wt + (size_t)3 * D * D;
    f16* Xf  = Ef + (size_t)L * DH;

    ecast_kernel<<<L * DH / 1024, 256, 0, stream>>>(E, Ef);
    xcast_kernel<<<dim3((unsigned)(plane / 1024), 3), 256, 0, stream>>>(q, k, v, Xf);
    wtrans_kernel<<<dim3(8, 8, 3), 256, 0, stream>>>(Wq, Wk, Wv, Wt);
    proj_gemm<<<dim3(1536), 256, 0, stream>>>(Xf, Wt, Qf, Kfp, Vtf);
    attn_kernel<<<dim3(L / 64, NH, B), 256, 0, stream>>>(Qf, Kfp, Vtf, Ef, out);
}

// Round 9
// 325.195 us; speedup vs baseline: 1.0174x; 1.0174x over previous
//
#include <hip/hip_runtime.h>
#include <hip/hip_bf16.h>
#include <math.h>

typedef _Float16 f16;
typedef __attribute__((ext_vector_type(8))) _Float16 f16x8;
typedef __attribute__((ext_vector_type(4))) _Float16 f16x4;
typedef __attribute__((ext_vector_type(4))) float f32x4;

namespace {
constexpr int B = 4, L = 2048, D = 512, NH = 8, DH = 64;
}

__device__ __forceinline__ float dpp_xor1(float x) {   // lane ^= 1 (quad_perm 1,0,3,2)
    return __int_as_float(__builtin_amdgcn_update_dpp(0, __float_as_int(x), 0xB1, 0xF, 0xF, true));
}
__device__ __forceinline__ float dpp_xor2(float x) {   // lane ^= 2 (quad_perm 2,3,0,1)
    return __int_as_float(__builtin_amdgcn_update_dpp(0, __float_as_int(x), 0x4E, 0xF, 0xF, true));
}
__device__ __forceinline__ float dpp_ror4(float x) {   // rotate 16-lane row by 4
    return __int_as_float(__builtin_amdgcn_update_dpp(0, __float_as_int(x), 0x124, 0xF, 0xF, true));
}
__device__ __forceinline__ float dpp_ror8(float x) {   // rotate 16-lane row by 8
    return __int_as_float(__builtin_amdgcn_update_dpp(0, __float_as_int(x), 0x128, 0xF, 0xF, true));
}

// ---- E cast: fp32 -> fp16 (131072 elems) ----
__global__ __launch_bounds__(256)
void ecast_kernel(const float* __restrict__ E, f16* __restrict__ Ef) {
    int i4 = (blockIdx.x * 256 + threadIdx.x) * 4;
    float4 x = *(const float4*)(E + i4);
    *(f16x4*)(Ef + i4) = (f16x4){(f16)x.x, (f16)x.y, (f16)x.z, (f16)x.w};
}

// ---- X cast: q/k/v fp32 -> f16 planes ----
__global__ __launch_bounds__(256)
void xcast_kernel(const float* __restrict__ q, const float* __restrict__ k,
                  const float* __restrict__ v, f16* __restrict__ Xf) {
    const int sel = blockIdx.y;
    const float* X = (sel == 0) ? q : (sel == 1) ? k : v;
    const size_t i4 = ((size_t)blockIdx.x * 256 + threadIdx.x) * 4;
    float4 x = *(const float4*)(X + i4);
    *(f16x4*)(Xf + (size_t)sel * ((size_t)B * L * D) + i4) =
        (f16x4){(f16)x.x, (f16)x.y, (f16)x.z, (f16)x.w};
}

// ---- W transpose+cast: W[k][n] fp32 -> Wt[sel][n][k] fp16, 64x64 tiles ----
__global__ __launch_bounds__(256)
void wtrans_kernel(const float* __restrict__ Wq, const float* __restrict__ Wk,
                   const float* __restrict__ Wv, f16* __restrict__ Wt) {
    __shared__ f16 Ws[64 * 65];
    const int sel = blockIdx.z;
    const float* W = (sel == 0) ? Wq : (sel == 1) ? Wk : Wv;
    f16* Wo = Wt + (size_t)sel * D * D;
    const int k0 = blockIdx.x * 64, n0 = blockIdx.y * 64;
    const int t = threadIdx.x;
#pragma unroll
    for (int i = 0; i < 16; ++i) {
        int idx = 256 * i + t;
        int r = idx >> 6, c = idx & 63;
        Ws[r * 65 + c] = (f16)W[(size_t)(k0 + r) * D + n0 + c];
    }
    __syncthreads();
    const int c = t >> 2, kseg = t & 3;
    f16x8 r0, r1;
#pragma unroll
    for (int j = 0; j < 8; ++j) r0[j] = Ws[(kseg * 16 + j) * 65 + c];
#pragma unroll
    for (int j = 0; j < 8; ++j) r1[j] = Ws[(kseg * 16 + 8 + j) * 65 + c];
    f16* o = Wo + (size_t)(n0 + c) * D + k0 + kseg * 16;
    *(f16x8*)o = r0;
    *(f16x8*)(o + 8) = r1;
}

// ---- fused projections: C = Xf(f16) . W, fp16 MFMA, 128m x 128n tiles ----
// 2 heads per block halves the 8x-redundant X panel re-fetch of the 64-col
// version. 2x2 wave grid, 64x64 per wave. Grid 768 = 8 XCDs x 96, by-fast so
// the 12 blocks sharing an X panel run consecutively on one XCD.
__global__ __launch_bounds__(256, 3)
void proj_gemm(const f16* __restrict__ Xf, const f16* __restrict__ Wt,
               f16* __restrict__ Qf, f16* __restrict__ Kf, f16* __restrict__ Vtf) {
    __shared__ f16 Sh[2 * 128 * 72];             // As | Bs; epilogue reuses as Cs
    f16* As = Sh;
    f16* Bs = Sh + 128 * 72;
    const int flat = blockIdx.x;
    const int wg = (flat & 7) * 96 + (flat >> 3);    // 768 = 8 XCDs * 96
    const int by = wg % 12, bx = wg / 12;            // by fast: share X panel
    const int sel = by >> 2, hp = by & 3;            // head pair
    const int m0 = bx * 128;
    const f16* X = Xf + (size_t)sel * ((size_t)B * L * D);
    const f16* Bt = Wt + (size_t)sel * D * D + (size_t)hp * 128 * D;
    const int t = threadIdx.x, wid = t >> 6, lane = t & 63;
    const int quad = lane >> 4, col = lane & 15;
    const int wr = wid >> 1, wc = wid & 1;
    const int mw = wr * 64, nw = wc * 64;

    f32x4 acc[4][4];
#pragma unroll
    for (int i = 0; i < 4; ++i)
#pragma unroll
        for (int j = 0; j < 4; ++j) acc[i][j] = (f32x4){0.f, 0.f, 0.f, 0.f};

    f16x8 xa[4], breg[4];
    auto loadG = [&](int k0) {
#pragma unroll
        for (int i = 0; i < 4; ++i) {
            int idx = 256 * i + t;
            int r = idx >> 3, ch = idx & 7;            // 128 rows x 8 chunks
            xa[i]   = *(const f16x8*)(X  + (size_t)(m0 + r) * D + k0 + ch * 8);
            breg[i] = *(const f16x8*)(Bt + (size_t)r * D + k0 + ch * 8);
        }
    };
    auto storeL = [&]() {
#pragma unroll
        for (int i = 0; i < 4; ++i) {
            int idx = 256 * i + t;
            int r = idx >> 3, ch = idx & 7;
            *(f16x8*)(As + r * 72 + ch * 8) = xa[i];
            *(f16x8*)(Bs + r * 72 + ch * 8) = breg[i];
        }
    };

    loadG(0);
    for (int k0 = 0; k0 < D; k0 += 64) {
        __syncthreads();
        storeL();
        __syncthreads();
        if (k0 + 64 < D) loadG(k0 + 64);
#pragma unroll
        for (int ks = 0; ks < 2; ++ks) {
            f16x8 af[4], bf[4];
#pragma unroll
            for (int mt = 0; mt < 4; ++mt)
                af[mt] = *(const f16x8*)(As + (mw + mt * 16 + col) * 72 + quad * 8 + ks * 32);
#pragma unroll
            for (int nt = 0; nt < 4; ++nt)
                bf[nt] = *(const f16x8*)(Bs + (nw + nt * 16 + col) * 72 + quad * 8 + ks * 32);
#pragma unroll
            for (int mt = 0; mt < 4; ++mt)
#pragma unroll
                for (int nt = 0; nt < 4; ++nt)
                    acc[mt][nt] = __builtin_amdgcn_mfma_f32_16x16x32_f16(af[mt], bf[nt], acc[mt][nt], 0, 0, 0);
        }
    }

    if (sel < 2) {
        f16* Y = (sel == 0) ? Qf : Kf;
        const int h = hp * 2 + wc;                 // each wave's 64 cols = 1 head
#pragma unroll
        for (int mt = 0; mt < 4; ++mt)
#pragma unroll
            for (int nt = 0; nt < 4; ++nt)
#pragma unroll
                for (int reg = 0; reg < 4; ++reg) {
                    int m = m0 + mw + mt * 16 + quad * 4 + reg;
                    int bb = m >> 11, l = m & 2047, d = nt * 16 + col;
                    Y[((size_t)(bb * NH + h) * L + l) * DH + d] = (f16)acc[mt][nt][reg];
                }
    } else {
        __syncthreads();                 // frag reads done; reuse Sh as Cs[128][132]
        f16* Cs = Sh;
#pragma unroll
        for (int mt = 0; mt < 4; ++mt)
#pragma unroll
            for (int nt = 0; nt < 4; ++nt)
#pragma unroll
                for (int reg = 0; reg < 4; ++reg) {
                    int dd = nt * 16 + col;
                    int row = dd * 2 + wc;                 // (dh, head) interleaved
                    int lc = mw + mt * 16 + quad * 4 + reg;
                    Cs[row * 132 + lc] = (f16)acc[mt][nt][reg];
                }
        __syncthreads();
        const int row2 = t >> 1, half = t & 1;
        const int dd = row2 >> 1, hh = hp * 2 + (row2 & 1);
        const int bb = m0 >> 11, l0 = m0 & 2047;
        f16* Yv = Vtf + ((size_t)(bb * NH + hh) * DH + dd) * L + l0 + half * 64;
#pragma unroll
        for (int j = 0; j < 8; ++j)
            *(f16x8*)(Yv + j * 8) = *(const f16x8*)(Cs + row2 * 132 + half * 64 + j * 8);
    }
}

// ---- flash attention, fp16 MFMA, reg-prefetch K/V pipeline ----
// R4 base (verified 221us) with ONE structural change: the Srel diagonal
// scatter goes through a wave-private LDS bounce instead of 32 ds_bpermute
// shuffles. Write G rows (20 ds_write_b32, stride-85 f32 -> 2-way banks),
// read back at the diagonal address (16 ds_read_b32), unconditional adds on
// the 27/36 mask-free passes. Math bit-identical to R4. P-buf (f16, stride
// 72) overlays the G scratch (G fully consumed before P is written).
// Max tree all-DPP (ror4/ror8, R7-verified).
__global__ __launch_bounds__(256, 4)
void attn_kernel(const f16* __restrict__ Qf, const f16* __restrict__ Kf,
                 const f16* __restrict__ Vtf, const f16* __restrict__ Ef,
                 float* __restrict__ out) {
    __shared__ f16 KfS[64 * 72];
    __shared__ f16 VfS[64 * 72];
    __shared__ float Gbuf[4][16 * 85];   // 5440B/wave; P (f16) overlaps

    const int t = threadIdx.x, wid = t >> 6, lane = t & 63;
    const int quad = lane >> 4, col = lane & 15;
    const int l0w = blockIdx.x * 64 + wid * 16;
    const int h = blockIdx.y, bb = blockIdx.z;
    const size_t head = (size_t)(bb * NH + h) * (size_t)(L * DH);
    const f16* qf = Qf + head;
    const f16* kf = Kf + head;
    const f16* vt = Vtf + head;      // [dh][L]
    float* Gw = Gbuf[wid];
    f16* Pw = (f16*)Gw;

    const f16x8 ones8 = {(f16)1.f, (f16)1.f, (f16)1.f, (f16)1.f,
                         (f16)1.f, (f16)1.f, (f16)1.f, (f16)1.f};

    f16x8 qF[2], qS[2];
    {
        const int m = l0w + col;
        const int mS = min(m + 1, L - 1);   // row L never actually used
#pragma unroll
        for (int ks = 0; ks < 2; ++ks) {
            const int off = quad * 8 + ks * 32;
            qF[ks] = *(const f16x8*)(qf + (size_t)m * DH + off);
            qS[ks] = *(const f16x8*)(qf + (size_t)mS * DH + off);
        }
    }

    f16x8 kreg[2], vreg[2];
    auto loadKV = [&](int c0) {
#pragma unroll
        for (int i = 0; i < 2; ++i) {
            int idx = 256 * i + t;
            int r = idx >> 3, ch = idx & 7;
            kreg[i] = *(const f16x8*)(kf + (size_t)(c0 + r) * DH + ch * 8);
            vreg[i] = *(const f16x8*)(vt + (size_t)r * L + c0 + ch * 8);
        }
    };

    f32x4 O[4];
#pragma unroll
    for (int i = 0; i < 4; ++i) O[i] = (f32x4){0.f, 0.f, 0.f, 0.f};
    f32x4 sacc = (f32x4){0.f, 0.f, 0.f, 0.f};
    float mrow[4] = {-1e30f, -1e30f, -1e30f, -1e30f};

    loadKV(0);
    for (int c0 = 0; c0 < L; c0 += 64) {
        __syncthreads();   // all waves done reading previous K/V tile
#pragma unroll
        for (int i = 0; i < 2; ++i) {
            int idx = 256 * i + t;
            int r = idx >> 3, ch = idx & 7;
            *(f16x8*)(KfS + r * 72 + ch * 8) = kreg[i];
            *(f16x8*)(VfS + r * 72 + ch * 8) = vreg[i];
        }
        __syncthreads();
        if (c0 + 64 < L) loadKV(c0 + 64);   // prefetch; drains behind this tile's compute

        const int d0 = c0 - l0w;

        // ---- S = Q K^T (fp16 single pass) ----
        f32x4 S[4];
        __builtin_amdgcn_s_setprio(1);
#pragma unroll
        for (int ns = 0; ns < 4; ++ns) {
            S[ns] = (f32x4){0.f, 0.f, 0.f, 0.f};
#pragma unroll
            for (int ks = 0; ks < 2; ++ks) {
                f16x8 bh = *(const f16x8*)(KfS + (ns * 16 + col) * 72 + quad * 8 + ks * 32);
                S[ns] = __builtin_amdgcn_mfma_f32_16x16x32_f16(qF[ks], bh, S[ns], 0, 0, 0);
            }
        }
        __builtin_amdgcn_s_setprio(0);

        // ---- Srel: G = Q . E-window^T, diagonal scatter via LDS bounce ----
        const bool doA = (d0 <= 15);
        const bool doB = (d0 >= -61);
        const bool needmask = (d0 >= -48) && (d0 <= 16);
#pragma unroll 1
        for (int pass = 0; pass < 2; ++pass) {
            if ((pass == 0 && !doA) || (pass == 1 && !doB)) continue;
            const int jbase = (pass == 0) ? (d0 + L - 16) : (d0 - 17);
            f32x4 G[5];
#pragma unroll
            for (int g = 0; g < 5; ++g) {
                int er = min(max(jbase + g * 16 + col, 0), L - 1);
                G[g] = (f32x4){0.f, 0.f, 0.f, 0.f};
                const size_t eb = (size_t)er * DH + quad * 8;
#pragma unroll
                for (int ks = 0; ks < 2; ++ks) {
                    f16x8 e8 = *(const f16x8*)(Ef + eb + ks * 32);
                    G[g] = __builtin_amdgcn_mfma_f32_16x16x32_f16(
                               (pass == 0) ? qF[ks] : qS[ks], e8, G[g], 0, 0, 0);
                }
            }
            // write G rows: row r holds q_row(r) . E[jbase + jcol] at col jcol
#pragma unroll
            for (int g = 0; g < 5; ++g)
#pragma unroll
                for (int reg = 0; reg < 4; ++reg)
                    Gw[(quad * 4 + reg) * 85 + g * 16 + col] = G[g][reg];
            // wave-private write->read ordered by lgkmcnt
            if (!needmask) {
#pragma unroll
                for (int reg = 0; reg < 4; ++reg) {
                    const int r = quad * 4 + reg;
                    const float* gr = Gw + r * 85 + col - r + 15;
#pragma unroll
                    for (int ns = 0; ns < 4; ++ns)
                        S[ns][reg] += gr[ns * 16];
                }
            } else {
#pragma unroll
                for (int reg = 0; reg < 4; ++reg) {
                    const int r = quad * 4 + reg;
                    const float* gr = Gw + r * 85 + col - r + 15;
#pragma unroll
                    for (int ns = 0; ns < 4; ++ns) {
                        const int rel = d0 + ns * 16 + col - r;
                        const bool use = (pass == 0) ? (rel <= 0) : (rel >= 2);
                        if (use) S[ns][reg] += gr[ns * 16];
                    }
                }
            }
        }

        // ---- online softmax (rows in 16-lane groups); sum via MFMA below ----
#pragma unroll
        for (int reg = 0; reg < 4; ++reg) {
            float tm = fmaxf(fmaxf(S[0][reg], S[1][reg]), fmaxf(S[2][reg], S[3][reg]));
            tm = fmaxf(tm, dpp_xor1(tm));
            tm = fmaxf(tm, dpp_xor2(tm));
            tm = fmaxf(tm, dpp_ror4(tm));
            tm = fmaxf(tm, dpp_ror8(tm));
            const float mnew  = fmaxf(mrow[reg], tm);
            const float alpha = __expf(mrow[reg] - mnew);
            mrow[reg] = mnew;
            sacc[reg] *= alpha;
            const int r = quad * 4 + reg;
#pragma unroll
            for (int ns = 0; ns < 4; ++ns) {
                float p = __expf(S[ns][reg] - mnew);
                O[ns][reg] *= alpha;
                Pw[r * 72 + ns * 16 + col] = (f16)p;
            }
        }
        // wave-private Pw write->read ordered by lgkmcnt within the wave

        // ---- O += P V ; sacc += rowsum(P) via ones-fragment ----
        f16x8 pA[2];
        pA[0] = *(const f16x8*)(Pw + col * 72 + quad * 8);
        pA[1] = *(const f16x8*)(Pw + col * 72 + 32 + quad * 8);
        __builtin_amdgcn_s_setprio(1);
        sacc = __builtin_amdgcn_mfma_f32_16x16x32_f16(pA[0], ones8, sacc, 0, 0, 0);
        sacc = __builtin_amdgcn_mfma_f32_16x16x32_f16(pA[1], ones8, sacc, 0, 0, 0);
#pragma unroll
        for (int ns = 0; ns < 4; ++ns) {
#pragma unroll
            for (int ks = 0; ks < 2; ++ks) {
                f16x8 v8 = *(const f16x8*)(VfS + (ns * 16 + col) * 72 + quad * 8 + ks * 32);
                O[ns] = __builtin_amdgcn_mfma_f32_16x16x32_f16(pA[ks], v8, O[ns], 0, 0, 0);
            }
        }
        __builtin_amdgcn_s_setprio(0);
    }

#pragma unroll
    for (int reg = 0; reg < 4; ++reg) {
        const int l = l0w + quad * 4 + reg;
        const float inv = 1.0f / (sacc[reg] * 8.0f);
        float* o = out + ((size_t)bb * L + l) * D + h * DH;
#pragma unroll
        for (int ns = 0; ns < 4; ++ns)
            o[ns * 16 + col] = O[ns][reg] * inv;
    }
}

extern "C" void kernel_launch(void* const* d_in, const int* in_sizes, int n_in,
                              void* d_out, int out_size, void* d_ws, size_t ws_size,
                              hipStream_t stream) {
    const float* q  = (const float*)d_in[0];
    const float* k  = (const float*)d_in[1];
    const float* v  = (const float*)d_in[2];
    const float* Wq = (const float*)d_in[3];
    const float* Wk = (const float*)d_in[4];
    const float* Wv = (const float*)d_in[5];
    const float* E  = (const float*)d_in[6];
    float* out = (float*)d_out;

    // ws (fp16 elems): Qf|Kf|Vtf (4M each) | Wt (768K) | Ef (128K) | Xf (12M) ~ 50MB
    const size_t plane = (size_t)B * NH * L * DH;    // 4,194,304 (= B*L*D)
    f16* Qf  = (f16*)d_ws;
    f16* Kfp = Qf + plane;
    f16* Vtf = Kfp + plane;
    f16* Wt  = Vtf + plane;
    f16* Ef  = Wt + (size_t)3 * D * D;
    f16* Xf  = Ef + (size_t)L * DH;

    ecast_kernel<<<L * DH / 1024, 256, 0, stream>>>(E, Ef);
    xcast_kernel<<<dim3((unsigned)(plane / 1024), 3), 256, 0, stream>>>(q, k, v, Xf);
    wtrans_kernel<<<dim3(8, 8, 3), 256, 0, stream>>>(Wq, Wk, Wv, Wt);
    proj_gemm<<<dim3(768), 256, 0, stream>>>(Xf, Wt, Qf, Kfp, Vtf);
    attn_kernel<<<dim3(L / 64, NH, B), 256, 0, stream>>>(Qf, Kfp, Vtf, Ef, out);
}